// Round 9
// baseline (1828.140 us; speedup 1.0000x reference)
//
#include <hip/hip_runtime.h>
#include <math.h>

// DEQ fixed-point via Broyden. B=256, D=2048, T=12.
// R9: merged per-iteration kernel (GEMM phase + device-scope counter barrier +
// Gram-space Broyden phase), 13 launches instead of 26. bf16 gx planes.
// Candidate outputs (x_k + g_k) stored fp32 per step; final = copy argmin plane.
// GEMM: 2-term split A=[x_hi|x_lo] x bf16 W (K=4096), M-resident mtile=256,
// ntile=64, split-K=8 -> 256 blocks x 512 thr; ks=bid&7 pins W panel per XCD L2.

#define DD 2048
#define KA 4096
#define KW 2048
#define BB 256
#define BD (BB * DD)
#define TT 12
#define NKS 8
#define KS 512             // KA/NKS
#define NITER 8            // KS/64
#define NBLK 256

// state layout (floats, per row, stride 1024)
#define ST_S   0           // 169
#define ST_A   169         // 12*13
#define ST_B   325         // 12*13
#define ST_PHI 481         // 13
#define ST_XI  494         // 13
#define ST_SZ  1024

typedef unsigned short ushort_t;
typedef __attribute__((ext_vector_type(8))) short short8;
typedef __attribute__((ext_vector_type(4))) float floatx4;

__device__ __forceinline__ ushort_t f2bf(float f) {
    unsigned int u = __float_as_uint(f);
    unsigned int r = (u + 0x7FFFu + ((u >> 16) & 1u)) >> 16;
    return (ushort_t)r;
}
__device__ __forceinline__ float bf2f(ushort_t h) {
    return __uint_as_float(((unsigned int)h) << 16);
}
__device__ __forceinline__ void gload_lds16(const void* g, void* l) {
    __builtin_amdgcn_global_load_lds(
        (const __attribute__((address_space(1))) unsigned int*)g,
        (__attribute__((address_space(3))) unsigned int*)l, 16, 0, 0);
}
__device__ __forceinline__ float wave_red(float v) {
#pragma unroll
    for (int off = 32; off > 0; off >>= 1) v += __shfl_down(v, off, 64);
    return v;
}

// ---------------- W & U -> bf16 transposed [n][k] planes ----------------
__global__ __launch_bounds__(256)
void convert_w(const float* __restrict__ W, const float* __restrict__ U,
               ushort_t* __restrict__ Wt, ushort_t* __restrict__ Ut) {
    const float* src = blockIdx.z ? U : W;
    ushort_t* dst = blockIdx.z ? Ut : Wt;
    __shared__ ushort_t Hs[64][65];
    const int tid = threadIdx.x;
    const int k0 = blockIdx.y * 64, n0 = blockIdx.x * 64;
    const int r = tid >> 4, c4 = (tid & 15) * 4;
#pragma unroll
    for (int i = 0; i < 4; ++i) {
        int kr = r + i * 16;
        float4 w = *(const float4*)(src + (size_t)(k0 + kr) * DD + n0 + c4);
        Hs[kr][c4 + 0] = f2bf(w.x); Hs[kr][c4 + 1] = f2bf(w.y);
        Hs[kr][c4 + 2] = f2bf(w.z); Hs[kr][c4 + 3] = f2bf(w.w);
    }
    __syncthreads();
#pragma unroll
    for (int i = 0; i < 4; ++i) {
        int nr = r + i * 16;
        ushort4 hv = { Hs[c4+0][nr], Hs[c4+1][nr], Hs[c4+2][nr], Hs[c4+3][nr] };
        *(ushort4*)(dst + (size_t)(n0 + nr) * KW + (size_t)(k0 + c4)) = hv;
    }
}

// ---------------- init: Axx = [hi|lo](xin); zero state+scal+ctrl ----------------
__global__ void init_misc(const float* __restrict__ xin, ushort_t* __restrict__ Axx,
                          float* __restrict__ stbase) {
    const int i4 = blockIdx.x * 256 + threadIdx.x;   // 512 blocks
    const int idx = i4 * 4;
    const int m = idx >> 11, col = idx & 2047;
    float4 xv = ((const float4*)xin)[i4];
    float a[4] = {xv.x, xv.y, xv.z, xv.w};
    ushort_t hh[4], ll[4];
#pragma unroll
    for (int j = 0; j < 4; ++j) { hh[j] = f2bf(a[j]); ll[j] = f2bf(a[j] - bf2f(hh[j])); }
    ushort4 h = {hh[0],hh[1],hh[2],hh[3]}, l = {ll[0],ll[1],ll[2],ll[3]};
    size_t ab = (size_t)m * KA + col;
    *(ushort4*)(Axx + ab) = h; *(ushort4*)(Axx + ab + DD) = l;
    if (i4 < 65548) {            // state 262144 + scal 32 + ctrl 16 floats
        float4 z = {0.f, 0.f, 0.f, 0.f};
        ((float4*)stbase)[i4] = z;
    }
}

// ---------------- merged iteration: GEMM -> grid barrier -> Broyden ----------------
// 256 blocks x 512 thr. Phase A: bn=(bid>>3)*64, ks=bid&7 (W panel per XCD L2).
// Phase B: block bid owns batch row bid. k==0: epi0 path; k>=1: Gram Broyden.
__global__ __launch_bounds__(512)
void deq_iter(const ushort_t* __restrict__ Aop, const ushort_t* __restrict__ Wop,
              float* __restrict__ y, const float* __restrict__ bias,
              float* __restrict__ c, ushort_t* __restrict__ gxp,
              ushort_t* __restrict__ Azz, float* __restrict__ cand,
              float* __restrict__ state, float* __restrict__ scal,
              unsigned* __restrict__ ctrl, int k)
{
    __shared__ ushort_t As[2][256 * 64];   // 2 x 32 KB
    __shared__ ushort_t Bs[2][64 * 64];    // 2 x 8 KB
    __shared__ float red[8][16];
    __shared__ float dots[14];
    __shared__ float Sl[169], Al[156], Bl[156], PHl[13], XIl[13];
    __shared__ float newA[14], newB[14], nphi[14];
    __shared__ double dyv[13], dxtu[12], dvdg[12], dcgx[13], dden[1];

    const int tid = threadIdx.x;
    const int lane = tid & 63, w = tid >> 6;
    const int bid = blockIdx.x;

    // ================= phase A: GEMM =================
    {
        const int bn = (bid >> 3) * 64;
        const int ks = bid & 7;
        const int waveM = w >> 1, waveN = w & 1;

        const int srow = tid >> 3;
        const int sg = (tid & 7) ^ (srow & 7);
        const ushort_t* Ag = Aop + (size_t)srow * KA + ks * KS + sg * 8;
        const ushort_t* Bg = Wop + (size_t)(bn + srow) * KW + (ks & 3) * KS + sg * 8;
        const size_t rs64 = (size_t)64 * KA;

        const int q = lane >> 4, rl = lane & 15;
        int offA[2][4], offB[2][2];
#pragma unroll
        for (int kk = 0; kk < 2; ++kk) {
            int j = kk * 4 + q;
#pragma unroll
            for (int mi = 0; mi < 4; ++mi) {
                int m = waveM * 64 + mi * 16 + rl;
                offA[kk][mi] = (m * 8 + (j ^ (m & 7))) * 8;
            }
#pragma unroll
            for (int ni = 0; ni < 2; ++ni) {
                int n = waveN * 32 + ni * 16 + rl;
                offB[kk][ni] = (n * 8 + (j ^ (n & 7))) * 8;
            }
        }

        floatx4 acc[4][2];
#pragma unroll
        for (int mi = 0; mi < 4; ++mi)
#pragma unroll
            for (int ni = 0; ni < 2; ++ni) acc[mi][ni] = (floatx4){0.f,0.f,0.f,0.f};

        gload_lds16(Ag,            As[0] + tid * 8);
        gload_lds16(Ag + rs64,     As[0] + (512 + tid) * 8);
        gload_lds16(Ag + 2 * rs64, As[0] + (1024 + tid) * 8);
        gload_lds16(Ag + 3 * rs64, As[0] + (1536 + tid) * 8);
        gload_lds16(Bg,            Bs[0] + tid * 8);
        Ag += 64; Bg += 64;
        __syncthreads();

        for (int it = 0; it < NITER; ++it) {
            const int cur = it & 1, nxt = cur ^ 1;
            if (it + 1 < NITER) {
                gload_lds16(Ag,            As[nxt] + tid * 8);
                gload_lds16(Ag + rs64,     As[nxt] + (512 + tid) * 8);
                gload_lds16(Ag + 2 * rs64, As[nxt] + (1024 + tid) * 8);
                gload_lds16(Ag + 3 * rs64, As[nxt] + (1536 + tid) * 8);
                gload_lds16(Bg,            Bs[nxt] + tid * 8);
                Ag += 64; Bg += 64;
            }
            const ushort_t* Ab = As[cur];
            const ushort_t* Bb = Bs[cur];
#pragma unroll
            for (int kk = 0; kk < 2; ++kk) {
                short8 b0 = *(const short8*)(Bb + offB[kk][0]);
                short8 b1 = *(const short8*)(Bb + offB[kk][1]);
#pragma unroll
                for (int mi = 0; mi < 4; ++mi) {
                    short8 a = *(const short8*)(Ab + offA[kk][mi]);
                    acc[mi][0] = __builtin_amdgcn_mfma_f32_16x16x32_bf16(a, b0, acc[mi][0], 0, 0, 0);
                    acc[mi][1] = __builtin_amdgcn_mfma_f32_16x16x32_bf16(a, b1, acc[mi][1], 0, 0, 0);
                }
            }
            __syncthreads();
        }

        float* yp = y + (size_t)ks * BD;
        const int mb = waveM * 64 + q * 4;
        const int nb = bn + waveN * 32 + rl;
#pragma unroll
        for (int mi = 0; mi < 4; ++mi)
#pragma unroll
            for (int r = 0; r < 4; ++r) {
                yp[(size_t)(mb + mi * 16 + r) * DD + nb]      = acc[mi][0][r];
                yp[(size_t)(mb + mi * 16 + r) * DD + nb + 16] = acc[mi][1][r];
            }
    }

    // ================= grid barrier (device-scope) =================
    __threadfence();
    __syncthreads();
    if (tid == 0) {
        __hip_atomic_fetch_add(&ctrl[k], 1u, __ATOMIC_ACQ_REL, __HIP_MEMORY_SCOPE_AGENT);
        while (__hip_atomic_load(&ctrl[k], __ATOMIC_ACQUIRE, __HIP_MEMORY_SCOPE_AGENT) < NBLK)
            __builtin_amdgcn_s_sleep(2);
    }
    __syncthreads();
    __threadfence();

    // ================= phase B: row bid =================
    const int b = bid;
    const int col = tid * 4;
    const size_t base = (size_t)b * DD + col;

    float4 pre;
    {
        float4 s = {0.f, 0.f, 0.f, 0.f};
#pragma unroll
        for (int ss = 0; ss < NKS; ++ss) {
            float4 v = *(const float4*)(y + (size_t)ss * BD + base);
            s.x += v.x; s.y += v.y; s.z += v.z; s.w += v.w;
        }
        pre = s;
    }

    if (k == 0) {
        float4 bv = *(const float4*)(bias + col);
        float4 cc = { pre.x + bv.x, pre.y + bv.y, pre.z + bv.z, pre.w + bv.w };
        *(float4*)(c + base) = cc;
        float4 g = { tanhf(cc.x), tanhf(cc.y), tanhf(cc.z), tanhf(cc.w) };
        ushort4 gs = { f2bf(g.x), f2bf(g.y), f2bf(g.z), f2bf(g.w) };
        *(ushort4*)(gxp + base) = gs;                 // gx plane 0 (bf16)
        *(float4*)(cand + base) = g;                  // cand_0 = x_0 + g_0 = g_0

        float a[4] = {g.x, g.y, g.z, g.w};
        ushort_t hh[4], ll[4];
#pragma unroll
        for (int j = 0; j < 4; ++j) { hh[j] = f2bf(a[j]); ll[j] = f2bf(a[j] - bf2f(hh[j])); }
        ushort4 h = {hh[0],hh[1],hh[2],hh[3]}, l = {ll[0],ll[1],ll[2],ll[3]};
        size_t ab = (size_t)b * KA + col;
        *(ushort4*)(Azz + ab) = h; *(ushort4*)(Azz + ab + DD) = l;

        float pd = g.x*g.x + g.y*g.y + g.z*g.z + g.w*g.w;
        pd = wave_red(pd);
        if (lane == 0) red[w][0] = pd;
        __syncthreads();
        if (tid == 0) {
            float t = 0.f;
#pragma unroll
            for (int w2 = 0; w2 < 8; ++w2) t += red[w2][0];
            float* stb = state + (size_t)b * ST_SZ;
            stb[ST_S + 0]   = t;
            stb[ST_PHI + 0] = 1.f;
            stb[ST_XI + 0]  = 1.f;
            atomicAdd(&scal[0], t);
        }
        return;
    }

    const int p = k - 1;
    float* stb = state + (size_t)b * ST_SZ;

    for (int i = tid; i < 169; i += 512) Sl[i] = stb[ST_S + i];
    for (int i = tid; i < 156; i += 512) { Al[i] = stb[ST_A + i]; Bl[i] = stb[ST_B + i]; }
    if (tid < 13) { PHl[tid] = stb[ST_PHI + tid]; XIl[tid] = stb[ST_XI + tid]; }

    {
        float4 cv = *(const float4*)(c + base);
        pre.x += cv.x; pre.y += cv.y; pre.z += cv.z; pre.w += cv.w;
    }

    float4 G[12];
#pragma unroll
    for (int j = 0; j < 12; ++j)
        if (j < k) {
            ushort4 gu = *(const ushort4*)(gxp + (size_t)j * BD + base);
            G[j] = (float4){ bf2f(gu.x), bf2f(gu.y), bf2f(gu.z), bf2f(gu.w) };
        }

    __syncthreads();

    float4 x = {0.f, 0.f, 0.f, 0.f};
#pragma unroll
    for (int j = 0; j < 12; ++j)
        if (j < k) {
            float xc = XIl[j];
            x.x = fmaf(xc, G[j].x, x.x); x.y = fmaf(xc, G[j].y, x.y);
            x.z = fmaf(xc, G[j].z, x.z); x.w = fmaf(xc, G[j].w, x.w);
        }
    float4 gk = { tanhf(pre.x) - x.x, tanhf(pre.y) - x.y,
                  tanhf(pre.z) - x.z, tanhf(pre.w) - x.w };

#pragma unroll
    for (int j = 0; j < 12; ++j)
        if (j < k) {
            float pd = G[j].x*gk.x + G[j].y*gk.y + G[j].z*gk.z + G[j].w*gk.w;
            pd = wave_red(pd);
            if (lane == 0) red[w][j] = pd;
        }
    {
        float pdk = gk.x*gk.x + gk.y*gk.y + gk.z*gk.z + gk.w*gk.w;
        pdk = wave_red(pdk);
        if (lane == 0) red[w][k] = pdk;
    }
    __syncthreads();
    if (tid <= k) {
        float s = 0.f;
#pragma unroll
        for (int w2 = 0; w2 < 8; ++w2) s += red[w2][tid];
        dots[tid] = s;
        if (tid == k) atomicAdd(&scal[k], s);
    }
    __syncthreads();

    // ---- scalar solve (fp64) ----
    if (tid < k) {
        double s = 0.0;
        for (int j = 0; j < k; ++j) s += (double)Sl[tid*13 + j] * (double)PHl[j];
        dyv[tid] = s;
    }
    __syncthreads();
    if (tid < p) {
        double sx = 0.0, sv = 0.0;
        for (int j = 0; j < k; ++j) {
            sx += (double)Al[tid*13 + j] * dyv[j];
            sv += (double)Bl[tid*13 + j] * ((double)dots[j] - (double)Sl[j*13 + (k-1)]);
        }
        dxtu[tid] = sx; dvdg[tid] = sv;
    }
    __syncthreads();
    if (tid < k) {
        double s = -(double)PHl[tid];
        for (int t = 0; t < p; ++t) s += dxtu[t] * (double)Bl[t*13 + tid];
        newB[tid] = (float)s;
    }
    __syncthreads();
    if (tid == 0) {
        double s = 0.0;
        for (int j = 0; j < k; ++j)
            s += (double)newB[j] * ((double)dots[j] - (double)Sl[j*13 + (k-1)]);
        dden[0] = s;
    }
    __syncthreads();
    if (tid <= k) {
        double s = (double)((tid < 13) ? PHl[tid] : 0.f);
        if (tid == k)     s += 1.0;
        if (tid == k - 1) s -= 1.0;
        for (int t = 0; t < p; ++t) s -= dvdg[t] * (double)Al[t*13 + tid];
        newA[tid] = (float)(s / dden[0]);
    }
    if (tid >= 32 && tid < 32 + p) {
        int t = tid - 32;
        double s = 0.0;
        for (int j = 0; j < k; ++j) s += (double)Bl[t*13 + j] * (double)dots[j];
        dcgx[t] = s;
    }
    if (tid == 63) {
        double s = 0.0;
        for (int j = 0; j < k; ++j) s += (double)newB[j] * (double)dots[j];
        dcgx[p] = s;
    }
    __syncthreads();
    if (tid <= k) {
        double s = (tid == k) ? 1.0 : 0.0;
        for (int t = 0; t < p; ++t) s -= dcgx[t] * (double)Al[t*13 + tid];
        s -= dcgx[p] * (double)newA[tid];
        nphi[tid] = (float)s;
    }
    __syncthreads();

    if (tid <= k) {
        stb[ST_S + k*13 + tid] = dots[tid];
        stb[ST_S + tid*13 + k] = dots[tid];
        stb[ST_A + p*13 + tid] = newA[tid];
        stb[ST_PHI + tid] = nphi[tid];
        float xi_old = (tid < 13) ? XIl[tid] : 0.f;
        stb[ST_XI + tid] = xi_old + nphi[tid];
    }
    if (tid < k) stb[ST_B + p*13 + tid] = newB[tid];

    // candidate output for this step: x_k + g_k (fp32, exact w.r.t. trajectory)
    {
        float4 cd = { x.x + gk.x, x.y + gk.y, x.z + gk.z, x.w + gk.w };
        *(float4*)(cand + (size_t)k * BD + base) = cd;
    }

    // x_{k+1} = x_k + sum_{j<k} nphi_j g_j + nphi_k g_k
    float4 xn = x;
#pragma unroll
    for (int j = 0; j < 12; ++j)
        if (j < k) {
            float fc = nphi[j];
            xn.x = fmaf(fc, G[j].x, xn.x); xn.y = fmaf(fc, G[j].y, xn.y);
            xn.z = fmaf(fc, G[j].z, xn.z); xn.w = fmaf(fc, G[j].w, xn.w);
        }
    {
        float fk = nphi[k];
        xn.x = fmaf(fk, gk.x, xn.x); xn.y = fmaf(fk, gk.y, xn.y);
        xn.z = fmaf(fk, gk.z, xn.z); xn.w = fmaf(fk, gk.w, xn.w);
    }

    {
        ushort4 gs = { f2bf(gk.x), f2bf(gk.y), f2bf(gk.z), f2bf(gk.w) };
        *(ushort4*)(gxp + (size_t)k * BD + base) = gs;
    }

    float a[4] = {xn.x, xn.y, xn.z, xn.w};
    ushort_t hh[4], ll[4];
#pragma unroll
    for (int j = 0; j < 4; ++j) { hh[j] = f2bf(a[j]); ll[j] = f2bf(a[j] - bf2f(hh[j])); }
    ushort4 h = {hh[0],hh[1],hh[2],hh[3]}, l = {ll[0],ll[1],ll[2],ll[3]};
    size_t ab = (size_t)b * KA + col;
    *(ushort4*)(Azz + ab) = h; *(ushort4*)(Azz + ab + DD) = l;
}

// ---------------- final: argmin obj; out = cand[bk] ----------------
__global__ __launch_bounds__(256)
void final_out(const float* __restrict__ cand, const float* __restrict__ scal,
               float* __restrict__ out) {
    const int i4 = blockIdx.x * 256 + threadIdx.x;
    float best = scal[0];
    int bk = 0;
#pragma unroll
    for (int k = 1; k <= TT; ++k) {
        float o = scal[k];
        if (o < best) { best = o; bk = k; }
    }
    ((float4*)out)[i4] = ((const float4*)(cand + (size_t)bk * BD))[i4];
}

// ---------------- launch ----------------
extern "C" void kernel_launch(void* const* d_in, const int* in_sizes, int n_in,
                              void* d_out, int out_size, void* d_ws, size_t ws_size,
                              hipStream_t stream) {
    const float* xin  = (const float*)d_in[0];
    const float* W    = (const float*)d_in[2];
    const float* U    = (const float*)d_in[3];
    const float* bias = (const float*)d_in[4];
    float* out = (float*)d_out;

    float* ws = (float*)d_ws;
    float* c      = ws;                                   // 1 BD
    float* y      = ws + 1 * (size_t)BD;                  // 8 BD
    float* cand   = ws + 9 * (size_t)BD;                  // 13 BD
    ushort_t* gxp = (ushort_t*)(ws + 22 * (size_t)BD);    // 13 planes u16 = 6.5 BD
    ushort_t* Axx = (ushort_t*)(ws + 29 * (size_t)BD);    // 1 BD
    ushort_t* Azz = (ushort_t*)(ws + 30 * (size_t)BD);    // 1 BD
    ushort_t* Wt  = (ushort_t*)(ws + 31 * (size_t)BD);    // 4 BD
    ushort_t* Ut  = (ushort_t*)(ws + 35 * (size_t)BD);    // 4 BD
    float* state  = ws + 39 * (size_t)BD;                 // 0.5 BD
    float* scal   = state + (size_t)BB * ST_SZ;           // 32 floats
    unsigned* ctrl = (unsigned*)(scal + 32);              // 16 u32 (zeroed by init)

    convert_w<<<dim3(32, 32, 2), 256, 0, stream>>>(W, U, Wt, Ut);
    init_misc<<<512, 256, 0, stream>>>(xin, Axx, state);

    // k=0: y = xin@U ; phase B computes c, g0, cand0, Azz, state init
    deq_iter<<<NBLK, 512, 0, stream>>>(Axx, Ut, y, bias, c, gxp, Azz, cand,
                                       state, scal, ctrl, 0);
    for (int k = 1; k <= TT; ++k)
        deq_iter<<<NBLK, 512, 0, stream>>>(Azz, Wt, y, bias, c, gxp, Azz, cand,
                                           state, scal, ctrl, k);

    final_out<<<512, 256, 0, stream>>>(cand, scal, out);
}

// Round 10
// 455.491 us; speedup vs baseline: 4.0136x; 4.0136x over previous
//
#include <hip/hip_runtime.h>
#include <math.h>

// DEQ fixed-point via Broyden. B=256, D=2048, T=12.
// R10: R8 separate-kernel structure (grid barriers in-kernel are 5-10x slower
// on MI355X — confirmed R5+R9: agent-scope acquire invalidates per-XCD L2).
// GEMM upgraded to 32x32x16 MFMA, 64x64 wave-tiles (2x arithmetic intensity
// per LDS byte vs 64x32). 2-term split A=[x_hi|x_lo] x bf16 W (K=4096),
// M-resident mtile=256, ntile=64, split-K=8 -> 256 blocks x 256 thr.
// Broyden in Gram space, bf16 g-planes, XSN coeff snapshots for final argmin.

#define DD 2048
#define KA 4096
#define KW 2048
#define BB 256
#define BD (BB * DD)
#define TT 12
#define NKS 8
#define KS 512             // KA/NKS
#define NITER 8            // KS/64

// state layout (floats, per row, stride 1024)
#define ST_S   0           // 169
#define ST_A   169         // 12*13
#define ST_B   325         // 12*13
#define ST_PHI 481         // 13
#define ST_XI  494         // 13
#define ST_XSN 507         // 13*13 -> ends 676
#define ST_SZ  1024

typedef unsigned short ushort_t;
typedef __attribute__((ext_vector_type(8))) short short8;
typedef __attribute__((ext_vector_type(16))) float floatx16;

__device__ __forceinline__ ushort_t f2bf(float f) {
    unsigned int u = __float_as_uint(f);
    unsigned int r = (u + 0x7FFFu + ((u >> 16) & 1u)) >> 16;
    return (ushort_t)r;
}
__device__ __forceinline__ float bf2f(ushort_t h) {
    return __uint_as_float(((unsigned int)h) << 16);
}
__device__ __forceinline__ void gload_lds16(const void* g, void* l) {
    __builtin_amdgcn_global_load_lds(
        (const __attribute__((address_space(1))) unsigned int*)g,
        (__attribute__((address_space(3))) unsigned int*)l, 16, 0, 0);
}
__device__ __forceinline__ float wave_red(float v) {
#pragma unroll
    for (int off = 32; off > 0; off >>= 1) v += __shfl_down(v, off, 64);
    return v;
}

// ---------------- W & U -> bf16 transposed [n][k] planes ----------------
__global__ __launch_bounds__(256)
void convert_w(const float* __restrict__ W, const float* __restrict__ U,
               ushort_t* __restrict__ Wt, ushort_t* __restrict__ Ut) {
    const float* src = blockIdx.z ? U : W;
    ushort_t* dst = blockIdx.z ? Ut : Wt;
    __shared__ ushort_t Hs[64][65];
    const int tid = threadIdx.x;
    const int k0 = blockIdx.y * 64, n0 = blockIdx.x * 64;
    const int r = tid >> 4, c4 = (tid & 15) * 4;
#pragma unroll
    for (int i = 0; i < 4; ++i) {
        int kr = r + i * 16;
        float4 w = *(const float4*)(src + (size_t)(k0 + kr) * DD + n0 + c4);
        Hs[kr][c4 + 0] = f2bf(w.x); Hs[kr][c4 + 1] = f2bf(w.y);
        Hs[kr][c4 + 2] = f2bf(w.z); Hs[kr][c4 + 3] = f2bf(w.w);
    }
    __syncthreads();
#pragma unroll
    for (int i = 0; i < 4; ++i) {
        int nr = r + i * 16;
        ushort4 hv = { Hs[c4+0][nr], Hs[c4+1][nr], Hs[c4+2][nr], Hs[c4+3][nr] };
        *(ushort4*)(dst + (size_t)(n0 + nr) * KW + (size_t)(k0 + c4)) = hv;
    }
}

// ---------------- init: Axx = [hi|lo](xin); zero state+scal ----------------
__global__ void init_misc(const float* __restrict__ xin, ushort_t* __restrict__ Axx,
                          float* __restrict__ stbase) {
    const int i4 = blockIdx.x * 256 + threadIdx.x;   // 512 blocks
    const int idx = i4 * 4;
    const int m = idx >> 11, col = idx & 2047;
    float4 xv = ((const float4*)xin)[i4];
    float a[4] = {xv.x, xv.y, xv.z, xv.w};
    ushort_t hh[4], ll[4];
#pragma unroll
    for (int j = 0; j < 4; ++j) { hh[j] = f2bf(a[j]); ll[j] = f2bf(a[j] - bf2f(hh[j])); }
    ushort4 h = {hh[0],hh[1],hh[2],hh[3]}, l = {ll[0],ll[1],ll[2],ll[3]};
    size_t ab = (size_t)m * KA + col;
    *(ushort4*)(Axx + ab) = h; *(ushort4*)(Axx + ab + DD) = l;
    if (i4 < 65544) {            // state 262144 + scal 32 floats
        float4 z = {0.f, 0.f, 0.f, 0.f};
        ((float4*)stbase)[i4] = z;
    }
}

// ---------------- M-resident GEMM, 32x32x16 MFMA, 64x64 wave-tiles ----------------
// 256 blocks x 256 thr (4 waves). bn=(bid>>3)*64, ks=bid&7.
// Wave w owns rows [w*64, w*64+64); all waves share the 64-wide n panel.
// A chunk 256x64 (32 KB) + B chunk 64x64 (8 KB), double-buffered (80 KB -> 2 blk/CU).
__global__ __launch_bounds__(256)
void gemm32(const ushort_t* __restrict__ Aop, const ushort_t* __restrict__ Wop,
            float* __restrict__ y) {
    __shared__ ushort_t As[2][256 * 64];
    __shared__ ushort_t Bs[2][64 * 64];
    const int tid = threadIdx.x;
    const int lane = tid & 63, w = tid >> 6;
    const int bid = blockIdx.x;
    const int bn = (bid >> 3) * 64;
    const int ks = bid & 7;

    // staging: thread t covers granule (row=t>>3 [+32*i], g=(t&7)^(row&7));
    // row&7 invariant under +32. LDS dest linear (wave-uniform + lane*16).
    const int srow = tid >> 3;
    const int sg = (tid & 7) ^ (srow & 7);
    const ushort_t* Ag = Aop + (size_t)srow * KA + ks * KS + sg * 8;
    const ushort_t* Bg = Wop + (size_t)(bn + srow) * KW + (ks & 3) * KS + sg * 8;
    const size_t ars32 = (size_t)32 * KA;
    const size_t brs32 = (size_t)32 * KW;

    // fragment offsets: lane l -> m/n = base + (l&31), k-granule j = kq*2 + (l>>5)
    const int q2 = lane >> 5, rl = lane & 31;
    int offA[4][2], offB[4][2];
#pragma unroll
    for (int kq = 0; kq < 4; ++kq) {
        int j = kq * 2 + q2;
#pragma unroll
        for (int mi = 0; mi < 2; ++mi) {
            int m = w * 64 + mi * 32 + rl;
            offA[kq][mi] = (m * 8 + (j ^ (m & 7))) * 8;
        }
#pragma unroll
        for (int ni = 0; ni < 2; ++ni) {
            int n = ni * 32 + rl;
            offB[kq][ni] = (n * 8 + (j ^ (n & 7))) * 8;
        }
    }

    floatx16 acc[2][2];
#pragma unroll
    for (int mi = 0; mi < 2; ++mi)
#pragma unroll
        for (int ni = 0; ni < 2; ++ni)
#pragma unroll
            for (int r = 0; r < 16; ++r) acc[mi][ni][r] = 0.f;

    // preload chunk 0
#pragma unroll
    for (int i = 0; i < 8; ++i)
        gload_lds16(Ag + (size_t)i * ars32, As[0] + ((i << 8) + tid) * 8);
#pragma unroll
    for (int i = 0; i < 2; ++i)
        gload_lds16(Bg + (size_t)i * brs32, Bs[0] + ((i << 8) + tid) * 8);
    Ag += 64; Bg += 64;
    __syncthreads();

    for (int it = 0; it < NITER; ++it) {
        const int cur = it & 1, nxt = cur ^ 1;
        if (it + 1 < NITER) {
#pragma unroll
            for (int i = 0; i < 8; ++i)
                gload_lds16(Ag + (size_t)i * ars32, As[nxt] + ((i << 8) + tid) * 8);
#pragma unroll
            for (int i = 0; i < 2; ++i)
                gload_lds16(Bg + (size_t)i * brs32, Bs[nxt] + ((i << 8) + tid) * 8);
            Ag += 64; Bg += 64;
        }
        const ushort_t* Ab = As[cur];
        const ushort_t* Bb = Bs[cur];
#pragma unroll
        for (int kq = 0; kq < 4; ++kq) {
            short8 a0 = *(const short8*)(Ab + offA[kq][0]);
            short8 a1 = *(const short8*)(Ab + offA[kq][1]);
            short8 b0 = *(const short8*)(Bb + offB[kq][0]);
            short8 b1 = *(const short8*)(Bb + offB[kq][1]);
            acc[0][0] = __builtin_amdgcn_mfma_f32_32x32x16_bf16(a0, b0, acc[0][0], 0, 0, 0);
            acc[0][1] = __builtin_amdgcn_mfma_f32_32x32x16_bf16(a0, b1, acc[0][1], 0, 0, 0);
            acc[1][0] = __builtin_amdgcn_mfma_f32_32x32x16_bf16(a1, b0, acc[1][0], 0, 0, 0);
            acc[1][1] = __builtin_amdgcn_mfma_f32_32x32x16_bf16(a1, b1, acc[1][1], 0, 0, 0);
        }
        __syncthreads();
    }

    // C/D 32x32: col = lane&31, row = (reg&3) + 8*(reg>>2) + 4*(lane>>5)  [m74/m101]
    float* yp = y + (size_t)ks * BD;
#pragma unroll
    for (int mi = 0; mi < 2; ++mi)
#pragma unroll
        for (int ni = 0; ni < 2; ++ni)
#pragma unroll
            for (int r = 0; r < 16; ++r) {
                int row = (r & 3) + 8 * (r >> 2) + 4 * q2;
                yp[(size_t)(w * 64 + mi * 32 + row) * DD + bn + ni * 32 + rl] = acc[mi][ni][r];
            }
}

// ---------------- step 0: c, g0 = tanh(c) (bf16 plane), Azz, state init ----------------
__global__ __launch_bounds__(512)
void epi0(const float* __restrict__ y, const float* __restrict__ bias,
          float* __restrict__ c, ushort_t* __restrict__ gxp,
          ushort_t* __restrict__ Azz, float* __restrict__ state,
          float* __restrict__ scal) {
    __shared__ float red[8];
    const int tid = threadIdx.x;
    const int b = blockIdx.x;
    const int col = tid * 4;
    const size_t base = (size_t)b * DD + col;

    float4 cc = *(const float4*)(bias + col);
#pragma unroll
    for (int s = 0; s < NKS; ++s) {
        float4 v = *(const float4*)(y + (size_t)s * BD + base);
        cc.x += v.x; cc.y += v.y; cc.z += v.z; cc.w += v.w;
    }
    *(float4*)(c + base) = cc;
    float4 g = { tanhf(cc.x), tanhf(cc.y), tanhf(cc.z), tanhf(cc.w) };
    ushort4 gs = { f2bf(g.x), f2bf(g.y), f2bf(g.z), f2bf(g.w) };
    *(ushort4*)(gxp + base) = gs;

    float a[4] = {g.x, g.y, g.z, g.w};
    ushort_t hh[4], ll[4];
#pragma unroll
    for (int j = 0; j < 4; ++j) { hh[j] = f2bf(a[j]); ll[j] = f2bf(a[j] - bf2f(hh[j])); }
    ushort4 h = {hh[0],hh[1],hh[2],hh[3]}, l = {ll[0],ll[1],ll[2],ll[3]};
    size_t ab = (size_t)b * KA + col;
    *(ushort4*)(Azz + ab) = h; *(ushort4*)(Azz + ab + DD) = l;

    float pd = g.x*g.x + g.y*g.y + g.z*g.z + g.w*g.w;
    pd = wave_red(pd);
    if ((tid & 63) == 0) red[tid >> 6] = pd;
    __syncthreads();
    if (tid == 0) {
        float t = 0.f;
#pragma unroll
        for (int w2 = 0; w2 < 8; ++w2) t += red[w2];
        float* stb = state + (size_t)b * ST_SZ;
        stb[ST_S + 0]   = t;
        stb[ST_PHI + 0] = 1.f;
        stb[ST_XI + 0]  = 1.f;
        atomicAdd(&scal[0], t);
    }
}

// ---------------- Gram-space Broyden ----------------
__global__ __launch_bounds__(512)
void broyden_gram(const float* __restrict__ y, const float* __restrict__ c,
                  ushort_t* __restrict__ gxp, ushort_t* __restrict__ Azz,
                  float* __restrict__ state, float* __restrict__ scal, int k)
{
    __shared__ float red[8][16];
    __shared__ float dots[14];
    __shared__ float Sl[169], Al[156], Bl[156], PHl[13], XIl[13];
    __shared__ float newA[14], newB[14], nphi[14];
    __shared__ double dyv[13], dxtu[12], dvdg[12], dcgx[13], dden[1];
    const int tid = threadIdx.x;
    const int lane = tid & 63, w = tid >> 6;
    const int b = blockIdx.x;
    const int p = k - 1;
    float* stb = state + (size_t)b * ST_SZ;

    for (int i = tid; i < 169; i += 512) Sl[i] = stb[ST_S + i];
    for (int i = tid; i < 156; i += 512) { Al[i] = stb[ST_A + i]; Bl[i] = stb[ST_B + i]; }
    if (tid < 13) { PHl[tid] = stb[ST_PHI + tid]; XIl[tid] = stb[ST_XI + tid]; }

    const int col = tid * 4;
    const size_t base = (size_t)b * DD + col;
    float4 pre = *(const float4*)(c + base);
#pragma unroll
    for (int s = 0; s < NKS; ++s) {
        float4 v = *(const float4*)(y + (size_t)s * BD + base);
        pre.x += v.x; pre.y += v.y; pre.z += v.z; pre.w += v.w;
    }

    float4 G[12];
#pragma unroll
    for (int j = 0; j < 12; ++j)
        if (j < k) {
            ushort4 gu = *(const ushort4*)(gxp + (size_t)j * BD + base);
            G[j] = (float4){ bf2f(gu.x), bf2f(gu.y), bf2f(gu.z), bf2f(gu.w) };
        }

    __syncthreads();

    float4 x = {0.f, 0.f, 0.f, 0.f};
#pragma unroll
    for (int j = 0; j < 12; ++j)
        if (j < k) {
            float xc = XIl[j];
            x.x = fmaf(xc, G[j].x, x.x); x.y = fmaf(xc, G[j].y, x.y);
            x.z = fmaf(xc, G[j].z, x.z); x.w = fmaf(xc, G[j].w, x.w);
        }
    float4 gk = { tanhf(pre.x) - x.x, tanhf(pre.y) - x.y,
                  tanhf(pre.z) - x.z, tanhf(pre.w) - x.w };

#pragma unroll
    for (int j = 0; j < 12; ++j)
        if (j < k) {
            float pd = G[j].x*gk.x + G[j].y*gk.y + G[j].z*gk.z + G[j].w*gk.w;
            pd = wave_red(pd);
            if (lane == 0) red[w][j] = pd;
        }
    {
        float pdk = gk.x*gk.x + gk.y*gk.y + gk.z*gk.z + gk.w*gk.w;
        pdk = wave_red(pdk);
        if (lane == 0) red[w][k] = pdk;
    }
    __syncthreads();
    if (tid <= k) {
        float s = 0.f;
#pragma unroll
        for (int w2 = 0; w2 < 8; ++w2) s += red[w2][tid];
        dots[tid] = s;
        if (tid == k) atomicAdd(&scal[k], s);
    }
    __syncthreads();

    // ---- scalar solve (fp64) ----
    if (tid < k) {
        double s = 0.0;
        for (int j = 0; j < k; ++j) s += (double)Sl[tid*13 + j] * (double)PHl[j];
        dyv[tid] = s;
    }
    __syncthreads();
    if (tid < p) {
        double sx = 0.0, sv = 0.0;
        for (int j = 0; j < k; ++j) {
            sx += (double)Al[tid*13 + j] * dyv[j];
            sv += (double)Bl[tid*13 + j] * ((double)dots[j] - (double)Sl[j*13 + (k-1)]);
        }
        dxtu[tid] = sx; dvdg[tid] = sv;
    }
    __syncthreads();
    if (tid < k) {
        double s = -(double)PHl[tid];
        for (int t = 0; t < p; ++t) s += dxtu[t] * (double)Bl[t*13 + tid];
        newB[tid] = (float)s;
    }
    __syncthreads();
    if (tid == 0) {
        double s = 0.0;
        for (int j = 0; j < k; ++j)
            s += (double)newB[j] * ((double)dots[j] - (double)Sl[j*13 + (k-1)]);
        dden[0] = s;
    }
    __syncthreads();
    if (tid <= k) {
        double s = (double)((tid < 13) ? PHl[tid] : 0.f);
        if (tid == k)     s += 1.0;
        if (tid == k - 1) s -= 1.0;
        for (int t = 0; t < p; ++t) s -= dvdg[t] * (double)Al[t*13 + tid];
        newA[tid] = (float)(s / dden[0]);
    }
    if (tid >= 32 && tid < 32 + p) {
        int t = tid - 32;
        double s = 0.0;
        for (int j = 0; j < k; ++j) s += (double)Bl[t*13 + j] * (double)dots[j];
        dcgx[t] = s;
    }
    if (tid == 63) {
        double s = 0.0;
        for (int j = 0; j < k; ++j) s += (double)newB[j] * (double)dots[j];
        dcgx[p] = s;
    }
    __syncthreads();
    if (tid <= k) {
        double s = (tid == k) ? 1.0 : 0.0;
        for (int t = 0; t < p; ++t) s -= dcgx[t] * (double)Al[t*13 + tid];
        s -= dcgx[p] * (double)newA[tid];
        nphi[tid] = (float)s;
    }
    __syncthreads();

    if (tid <= k) {
        stb[ST_S + k*13 + tid] = dots[tid];
        stb[ST_S + tid*13 + k] = dots[tid];
        stb[ST_A + p*13 + tid] = newA[tid];
        stb[ST_PHI + tid] = nphi[tid];
        float xi_old = (tid < 13) ? XIl[tid] : 0.f;
        stb[ST_XI + tid] = xi_old + nphi[tid];
    }
    if (tid < k) stb[ST_B + p*13 + tid] = newB[tid];
    if (tid < 13) stb[ST_XSN + k*13 + tid] = XIl[tid];   // coeffs of x_k

    // x_{k+1} = x_k + sum_{j<k} nphi_j g_j + nphi_k g_k
    float4 xn = x;
#pragma unroll
    for (int j = 0; j < 12; ++j)
        if (j < k) {
            float fc = nphi[j];
            xn.x = fmaf(fc, G[j].x, xn.x); xn.y = fmaf(fc, G[j].y, xn.y);
            xn.z = fmaf(fc, G[j].z, xn.z); xn.w = fmaf(fc, G[j].w, xn.w);
        }
    {
        float fk = nphi[k];
        xn.x = fmaf(fk, gk.x, xn.x); xn.y = fmaf(fk, gk.y, xn.y);
        xn.z = fmaf(fk, gk.z, xn.z); xn.w = fmaf(fk, gk.w, xn.w);
    }

    {
        ushort4 gs = { f2bf(gk.x), f2bf(gk.y), f2bf(gk.z), f2bf(gk.w) };
        *(ushort4*)(gxp + (size_t)k * BD + base) = gs;
    }

    float a[4] = {xn.x, xn.y, xn.z, xn.w};
    ushort_t hh[4], ll[4];
#pragma unroll
    for (int j = 0; j < 4; ++j) { hh[j] = f2bf(a[j]); ll[j] = f2bf(a[j] - bf2f(hh[j])); }
    ushort4 h = {hh[0],hh[1],hh[2],hh[3]}, l = {ll[0],ll[1],ll[2],ll[3]};
    size_t ab = (size_t)b * KA + col;
    *(ushort4*)(Azz + ab) = h; *(ushort4*)(Azz + ab + DD) = l;
}

// ---------------- final: argmin obj; out = x_bk + g_bk from bf16 planes ----------------
__global__ __launch_bounds__(256)
void final_out(const ushort_t* __restrict__ gxp, const float* __restrict__ state,
               const float* __restrict__ scal, float* __restrict__ out) {
    const int i4 = blockIdx.x * 256 + threadIdx.x;
    float best = scal[0];
    int bk = 0;
#pragma unroll
    for (int k = 1; k <= TT; ++k) {
        float o = scal[k];
        if (o < best) { best = o; bk = k; }
    }
    const size_t idx = (size_t)i4 * 4;
    const int m = (int)(idx >> 11);
    const float* cf = state + (size_t)m * ST_SZ + ST_XSN + bk * 13;
    ushort4 gb = *(const ushort4*)(gxp + (size_t)bk * BD + idx);
    float4 r = { bf2f(gb.x), bf2f(gb.y), bf2f(gb.z), bf2f(gb.w) };
    for (int j = 0; j < bk; ++j) {
        float c1 = cf[j];
        ushort4 gu = *(const ushort4*)(gxp + (size_t)j * BD + idx);
        r.x = fmaf(c1, bf2f(gu.x), r.x); r.y = fmaf(c1, bf2f(gu.y), r.y);
        r.z = fmaf(c1, bf2f(gu.z), r.z); r.w = fmaf(c1, bf2f(gu.w), r.w);
    }
    ((float4*)out)[i4] = r;
}

// ---------------- launch ----------------
extern "C" void kernel_launch(void* const* d_in, const int* in_sizes, int n_in,
                              void* d_out, int out_size, void* d_ws, size_t ws_size,
                              hipStream_t stream) {
    const float* xin  = (const float*)d_in[0];
    const float* W    = (const float*)d_in[2];
    const float* U    = (const float*)d_in[3];
    const float* bias = (const float*)d_in[4];
    float* out = (float*)d_out;

    float* ws = (float*)d_ws;
    float* c      = ws;                                   // 1 BD
    float* y      = ws + 1 * (size_t)BD;                  // 8 BD
    ushort_t* gxp = (ushort_t*)(ws + 9 * (size_t)BD);     // 13 bf16 planes = 6.5 BD
    ushort_t* Axx = (ushort_t*)(ws + 16 * (size_t)BD);    // 1 BD
    ushort_t* Azz = (ushort_t*)(ws + 17 * (size_t)BD);    // 1 BD
    ushort_t* Wt  = (ushort_t*)(ws + 18 * (size_t)BD);    // [2048][2048]u16 = 4 BD
    ushort_t* Ut  = (ushort_t*)(ws + 22 * (size_t)BD);    // 4 BD
    float* state  = ws + 26 * (size_t)BD;                 // 0.5 BD
    float* scal   = state + (size_t)BB * ST_SZ;           // 32 floats

    convert_w<<<dim3(32, 32, 2), 256, 0, stream>>>(W, U, Wt, Ut);
    init_misc<<<512, 256, 0, stream>>>(xin, Axx, state);

    gemm32<<<NKS * 32, 256, 0, stream>>>(Axx, Ut, y);
    epi0<<<BB, 512, 0, stream>>>(y, bias, c, gxp, Azz, state, scal);

    for (int k = 1; k <= TT; ++k) {
        gemm32<<<NKS * 32, 256, 0, stream>>>(Azz, Wt, y);
        broyden_gram<<<BB, 512, 0, stream>>>(y, c, gxp, Azz, state, scal, k);
    }

    final_out<<<512, 256, 0, stream>>>(gxp, state, scal, out);
}

// Round 11
// 427.764 us; speedup vs baseline: 4.2737x; 1.0648x over previous
//
#include <hip/hip_runtime.h>
#include <math.h>

// DEQ fixed-point via Broyden. B=256, D=2048, T=12.
// R11 = R8's GEMM (16x16x32, mtile=256/8 waves — fastest measured) +
// R10's broyden (bf16 g-planes, halved plane traffic) + XSN coeff final.
// Grid barriers in-kernel are 5-10x slower on MI355X (R5+R9) — separate
// kernels per phase; launch boundary is the cheapest grid barrier.
// GEMM: 2-term split A=[x_hi|x_lo] x bf16 W (K=4096), split-K=8.

#define DD 2048
#define KA 4096
#define KW 2048
#define BB 256
#define BD (BB * DD)
#define TT 12
#define NKS 8
#define KS 512             // KA/NKS
#define NITER 8            // KS/64

// state layout (floats, per row, stride 1024)
#define ST_S   0           // 169
#define ST_A   169         // 12*13
#define ST_B   325         // 12*13
#define ST_PHI 481         // 13
#define ST_XI  494         // 13
#define ST_XSN 507         // 13*13
#define ST_SZ  1024

typedef unsigned short ushort_t;
typedef __attribute__((ext_vector_type(8))) short short8;
typedef __attribute__((ext_vector_type(4))) float floatx4;

__device__ __forceinline__ ushort_t f2bf(float f) {
    unsigned int u = __float_as_uint(f);
    unsigned int r = (u + 0x7FFFu + ((u >> 16) & 1u)) >> 16;
    return (ushort_t)r;
}
__device__ __forceinline__ float bf2f(ushort_t h) {
    return __uint_as_float(((unsigned int)h) << 16);
}
__device__ __forceinline__ void gload_lds16(const void* g, void* l) {
    __builtin_amdgcn_global_load_lds(
        (const __attribute__((address_space(1))) unsigned int*)g,
        (__attribute__((address_space(3))) unsigned int*)l, 16, 0, 0);
}
__device__ __forceinline__ float wave_red(float v) {
#pragma unroll
    for (int off = 32; off > 0; off >>= 1) v += __shfl_down(v, off, 64);
    return v;
}

// ---------------- W & U -> bf16 transposed [n][k] planes ----------------
__global__ __launch_bounds__(256)
void convert_w(const float* __restrict__ W, const float* __restrict__ U,
               ushort_t* __restrict__ Wt, ushort_t* __restrict__ Ut) {
    const float* src = blockIdx.z ? U : W;
    ushort_t* dst = blockIdx.z ? Ut : Wt;
    __shared__ ushort_t Hs[64][65];
    const int tid = threadIdx.x;
    const int k0 = blockIdx.y * 64, n0 = blockIdx.x * 64;
    const int r = tid >> 4, c4 = (tid & 15) * 4;
#pragma unroll
    for (int i = 0; i < 4; ++i) {
        int kr = r + i * 16;
        float4 w = *(const float4*)(src + (size_t)(k0 + kr) * DD + n0 + c4);
        Hs[kr][c4 + 0] = f2bf(w.x); Hs[kr][c4 + 1] = f2bf(w.y);
        Hs[kr][c4 + 2] = f2bf(w.z); Hs[kr][c4 + 3] = f2bf(w.w);
    }
    __syncthreads();
#pragma unroll
    for (int i = 0; i < 4; ++i) {
        int nr = r + i * 16;
        ushort4 hv = { Hs[c4+0][nr], Hs[c4+1][nr], Hs[c4+2][nr], Hs[c4+3][nr] };
        *(ushort4*)(dst + (size_t)(n0 + nr) * KW + (size_t)(k0 + c4)) = hv;
    }
}

// ---------------- init: Axx = [hi|lo](xin); zero state+scal ----------------
__global__ void init_misc(const float* __restrict__ xin, ushort_t* __restrict__ Axx,
                          float* __restrict__ stbase) {
    const int i4 = blockIdx.x * 256 + threadIdx.x;   // 512 blocks
    const int idx = i4 * 4;
    const int m = idx >> 11, col = idx & 2047;
    float4 xv = ((const float4*)xin)[i4];
    float a[4] = {xv.x, xv.y, xv.z, xv.w};
    ushort_t hh[4], ll[4];
#pragma unroll
    for (int j = 0; j < 4; ++j) { hh[j] = f2bf(a[j]); ll[j] = f2bf(a[j] - bf2f(hh[j])); }
    ushort4 h = {hh[0],hh[1],hh[2],hh[3]}, l = {ll[0],ll[1],ll[2],ll[3]};
    size_t ab = (size_t)m * KA + col;
    *(ushort4*)(Axx + ab) = h; *(ushort4*)(Axx + ab + DD) = l;
    if (i4 < 65544) {            // state 262144 + scal 32 floats
        float4 z = {0.f, 0.f, 0.f, 0.f};
        ((float4*)stbase)[i4] = z;
    }
}

// ---------------- M-resident 2-term split GEMM (R8 core, verified fastest) ----------------
// grid (32, 8): x = n-tile (64), y = ks. Slices 0..3 use A k in [0,2048) (x_hi),
// 4..7 use [2048,4096) (x_lo); W k-offset = (ks&3)*512 both times.
// 512 thr = 8 waves, wave-tile 64x32. A chunk 256x64 (32 KB) + B 64x64 (8 KB), dbuf.
__global__ __launch_bounds__(512)
void gemm_bf16s(const ushort_t* __restrict__ A, const ushort_t* __restrict__ Bt,
                float* __restrict__ y) {
    __shared__ ushort_t As[2][256 * 64];   // 2 x 32 KB
    __shared__ ushort_t Bs[2][64 * 64];    // 2 x 8 KB
    const int tid = threadIdx.x;
    const int lane = tid & 63, w = tid >> 6;
    const int bn = blockIdx.x * 64;
    const int ks = blockIdx.y;
    const int waveM = w >> 1, waveN = w & 1;

    const int srow = tid >> 3;
    const int sg = (tid & 7) ^ (srow & 7);
    const ushort_t* Ag = A  + (size_t)srow * KA + ks * KS + sg * 8;
    const ushort_t* Bg = Bt + (size_t)(bn + srow) * KW + (ks & 3) * KS + sg * 8;
    const size_t rs64 = (size_t)64 * KA;

    const int q = lane >> 4, rl = lane & 15;
    int offA[2][4], offB[2][2];
#pragma unroll
    for (int kk = 0; kk < 2; ++kk) {
        int j = kk * 4 + q;
#pragma unroll
        for (int mi = 0; mi < 4; ++mi) {
            int m = waveM * 64 + mi * 16 + rl;
            offA[kk][mi] = (m * 8 + (j ^ (m & 7))) * 8;
        }
#pragma unroll
        for (int ni = 0; ni < 2; ++ni) {
            int n = waveN * 32 + ni * 16 + rl;
            offB[kk][ni] = (n * 8 + (j ^ (n & 7))) * 8;
        }
    }

    floatx4 acc[4][2];
#pragma unroll
    for (int mi = 0; mi < 4; ++mi)
#pragma unroll
        for (int ni = 0; ni < 2; ++ni) acc[mi][ni] = (floatx4){0.f,0.f,0.f,0.f};

    gload_lds16(Ag,            As[0] + tid * 8);
    gload_lds16(Ag + rs64,     As[0] + (512 + tid) * 8);
    gload_lds16(Ag + 2 * rs64, As[0] + (1024 + tid) * 8);
    gload_lds16(Ag + 3 * rs64, As[0] + (1536 + tid) * 8);
    gload_lds16(Bg,            Bs[0] + tid * 8);
    Ag += 64; Bg += 64;
    __syncthreads();

    for (int it = 0; it < NITER; ++it) {
        const int cur = it & 1, nxt = cur ^ 1;
        if (it + 1 < NITER) {
            gload_lds16(Ag,            As[nxt] + tid * 8);
            gload_lds16(Ag + rs64,     As[nxt] + (512 + tid) * 8);
            gload_lds16(Ag + 2 * rs64, As[nxt] + (1024 + tid) * 8);
            gload_lds16(Ag + 3 * rs64, As[nxt] + (1536 + tid) * 8);
            gload_lds16(Bg,            Bs[nxt] + tid * 8);
            Ag += 64; Bg += 64;
        }
        const ushort_t* Ab = As[cur];
        const ushort_t* Bb = Bs[cur];
#pragma unroll
        for (int kk = 0; kk < 2; ++kk) {
            short8 b0 = *(const short8*)(Bb + offB[kk][0]);
            short8 b1 = *(const short8*)(Bb + offB[kk][1]);
#pragma unroll
            for (int mi = 0; mi < 4; ++mi) {
                short8 a = *(const short8*)(Ab + offA[kk][mi]);
                acc[mi][0] = __builtin_amdgcn_mfma_f32_16x16x32_bf16(a, b0, acc[mi][0], 0, 0, 0);
                acc[mi][1] = __builtin_amdgcn_mfma_f32_16x16x32_bf16(a, b1, acc[mi][1], 0, 0, 0);
            }
        }
        __syncthreads();
    }

    float* yp = y + (size_t)ks * BD;
    const int mb = waveM * 64 + q * 4;
    const int nb = bn + waveN * 32 + rl;
#pragma unroll
    for (int mi = 0; mi < 4; ++mi)
#pragma unroll
        for (int r = 0; r < 4; ++r) {
            yp[(size_t)(mb + mi * 16 + r) * DD + nb]      = acc[mi][0][r];
            yp[(size_t)(mb + mi * 16 + r) * DD + nb + 16] = acc[mi][1][r];
        }
}

// ---------------- step 0: c, g0 = tanh(c) (bf16 plane), Azz, state init ----------------
__global__ __launch_bounds__(512)
void epi0(const float* __restrict__ y, const float* __restrict__ bias,
          float* __restrict__ c, ushort_t* __restrict__ gxp,
          ushort_t* __restrict__ Azz, float* __restrict__ state,
          float* __restrict__ scal) {
    __shared__ float red[8];
    const int tid = threadIdx.x;
    const int b = blockIdx.x;
    const int col = tid * 4;
    const size_t base = (size_t)b * DD + col;

    float4 cc = *(const float4*)(bias + col);
#pragma unroll
    for (int s = 0; s < NKS; ++s) {
        float4 v = *(const float4*)(y + (size_t)s * BD + base);
        cc.x += v.x; cc.y += v.y; cc.z += v.z; cc.w += v.w;
    }
    *(float4*)(c + base) = cc;
    float4 g = { tanhf(cc.x), tanhf(cc.y), tanhf(cc.z), tanhf(cc.w) };
    ushort4 gs = { f2bf(g.x), f2bf(g.y), f2bf(g.z), f2bf(g.w) };
    *(ushort4*)(gxp + base) = gs;

    float a[4] = {g.x, g.y, g.z, g.w};
    ushort_t hh[4], ll[4];
#pragma unroll
    for (int j = 0; j < 4; ++j) { hh[j] = f2bf(a[j]); ll[j] = f2bf(a[j] - bf2f(hh[j])); }
    ushort4 h = {hh[0],hh[1],hh[2],hh[3]}, l = {ll[0],ll[1],ll[2],ll[3]};
    size_t ab = (size_t)b * KA + col;
    *(ushort4*)(Azz + ab) = h; *(ushort4*)(Azz + ab + DD) = l;

    float pd = g.x*g.x + g.y*g.y + g.z*g.z + g.w*g.w;
    pd = wave_red(pd);
    if ((tid & 63) == 0) red[tid >> 6] = pd;
    __syncthreads();
    if (tid == 0) {
        float t = 0.f;
#pragma unroll
        for (int w2 = 0; w2 < 8; ++w2) t += red[w2];
        float* stb = state + (size_t)b * ST_SZ;
        stb[ST_S + 0]   = t;
        stb[ST_PHI + 0] = 1.f;
        stb[ST_XI + 0]  = 1.f;
        atomicAdd(&scal[0], t);
    }
}

// ---------------- Gram-space Broyden (bf16 g-planes) ----------------
__global__ __launch_bounds__(512)
void broyden_gram(const float* __restrict__ y, const float* __restrict__ c,
                  ushort_t* __restrict__ gxp, ushort_t* __restrict__ Azz,
                  float* __restrict__ state, float* __restrict__ scal, int k)
{
    __shared__ float red[8][16];
    __shared__ float dots[14];
    __shared__ float Sl[169], Al[156], Bl[156], PHl[13], XIl[13];
    __shared__ float newA[14], newB[14], nphi[14];
    __shared__ double dyv[13], dxtu[12], dvdg[12], dcgx[13], dden[1];
    const int tid = threadIdx.x;
    const int lane = tid & 63, w = tid >> 6;
    const int b = blockIdx.x;
    const int p = k - 1;
    float* stb = state + (size_t)b * ST_SZ;

    for (int i = tid; i < 169; i += 512) Sl[i] = stb[ST_S + i];
    for (int i = tid; i < 156; i += 512) { Al[i] = stb[ST_A + i]; Bl[i] = stb[ST_B + i]; }
    if (tid < 13) { PHl[tid] = stb[ST_PHI + tid]; XIl[tid] = stb[ST_XI + tid]; }

    const int col = tid * 4;
    const size_t base = (size_t)b * DD + col;
    float4 pre = *(const float4*)(c + base);
#pragma unroll
    for (int s = 0; s < NKS; ++s) {
        float4 v = *(const float4*)(y + (size_t)s * BD + base);
        pre.x += v.x; pre.y += v.y; pre.z += v.z; pre.w += v.w;
    }

    float4 G[12];
#pragma unroll
    for (int j = 0; j < 12; ++j)
        if (j < k) {
            ushort4 gu = *(const ushort4*)(gxp + (size_t)j * BD + base);
            G[j] = (float4){ bf2f(gu.x), bf2f(gu.y), bf2f(gu.z), bf2f(gu.w) };
        }

    __syncthreads();

    float4 x = {0.f, 0.f, 0.f, 0.f};
#pragma unroll
    for (int j = 0; j < 12; ++j)
        if (j < k) {
            float xc = XIl[j];
            x.x = fmaf(xc, G[j].x, x.x); x.y = fmaf(xc, G[j].y, x.y);
            x.z = fmaf(xc, G[j].z, x.z); x.w = fmaf(xc, G[j].w, x.w);
        }
    float4 gk = { tanhf(pre.x) - x.x, tanhf(pre.y) - x.y,
                  tanhf(pre.z) - x.z, tanhf(pre.w) - x.w };

#pragma unroll
    for (int j = 0; j < 12; ++j)
        if (j < k) {
            float pd = G[j].x*gk.x + G[j].y*gk.y + G[j].z*gk.z + G[j].w*gk.w;
            pd = wave_red(pd);
            if (lane == 0) red[w][j] = pd;
        }
    {
        float pdk = gk.x*gk.x + gk.y*gk.y + gk.z*gk.z + gk.w*gk.w;
        pdk = wave_red(pdk);
        if (lane == 0) red[w][k] = pdk;
    }
    __syncthreads();
    if (tid <= k) {
        float s = 0.f;
#pragma unroll
        for (int w2 = 0; w2 < 8; ++w2) s += red[w2][tid];
        dots[tid] = s;
        if (tid == k) atomicAdd(&scal[k], s);
    }
    __syncthreads();

    // ---- scalar solve (fp64) ----
    if (tid < k) {
        double s = 0.0;
        for (int j = 0; j < k; ++j) s += (double)Sl[tid*13 + j] * (double)PHl[j];
        dyv[tid] = s;
    }
    __syncthreads();
    if (tid < p) {
        double sx = 0.0, sv = 0.0;
        for (int j = 0; j < k; ++j) {
            sx += (double)Al[tid*13 + j] * dyv[j];
            sv += (double)Bl[tid*13 + j] * ((double)dots[j] - (double)Sl[j*13 + (k-1)]);
        }
        dxtu[tid] = sx; dvdg[tid] = sv;
    }
    __syncthreads();
    if (tid < k) {
        double s = -(double)PHl[tid];
        for (int t = 0; t < p; ++t) s += dxtu[t] * (double)Bl[t*13 + tid];
        newB[tid] = (float)s;
    }
    __syncthreads();
    if (tid == 0) {
        double s = 0.0;
        for (int j = 0; j < k; ++j)
            s += (double)newB[j] * ((double)dots[j] - (double)Sl[j*13 + (k-1)]);
        dden[0] = s;
    }
    __syncthreads();
    if (tid <= k) {
        double s = (double)((tid < 13) ? PHl[tid] : 0.f);
        if (tid == k)     s += 1.0;
        if (tid == k - 1) s -= 1.0;
        for (int t = 0; t < p; ++t) s -= dvdg[t] * (double)Al[t*13 + tid];
        newA[tid] = (float)(s / dden[0]);
    }
    if (tid >= 32 && tid < 32 + p) {
        int t = tid - 32;
        double s = 0.0;
        for (int j = 0; j < k; ++j) s += (double)Bl[t*13 + j] * (double)dots[j];
        dcgx[t] = s;
    }
    if (tid == 63) {
        double s = 0.0;
        for (int j = 0; j < k; ++j) s += (double)newB[j] * (double)dots[j];
        dcgx[p] = s;
    }
    __syncthreads();
    if (tid <= k) {
        double s = (tid == k) ? 1.0 : 0.0;
        for (int t = 0; t < p; ++t) s -= dcgx[t] * (double)Al[t*13 + tid];
        s -= dcgx[p] * (double)newA[tid];
        nphi[tid] = (float)s;
    }
    __syncthreads();

    if (tid <= k) {
        stb[ST_S + k*13 + tid] = dots[tid];
        stb[ST_S + tid*13 + k] = dots[tid];
        stb[ST_A + p*13 + tid] = newA[tid];
        stb[ST_PHI + tid] = nphi[tid];
        float xi_old = (tid < 13) ? XIl[tid] : 0.f;
        stb[ST_XI + tid] = xi_old + nphi[tid];
    }
    if (tid < k) stb[ST_B + p*13 + tid] = newB[tid];
    if (tid < 13) stb[ST_XSN + k*13 + tid] = XIl[tid];   // coeffs of x_k

    // g_k plane always needed (final may pick bk=k)
    {
        ushort4 gs = { f2bf(gk.x), f2bf(gk.y), f2bf(gk.z), f2bf(gk.w) };
        *(ushort4*)(gxp + (size_t)k * BD + base) = gs;
    }

    if (k < TT) {   // x_{k+1}/Azz dead at k=TT
        float4 xn = x;
#pragma unroll
        for (int j = 0; j < 12; ++j)
            if (j < k) {
                float fc = nphi[j];
                xn.x = fmaf(fc, G[j].x, xn.x); xn.y = fmaf(fc, G[j].y, xn.y);
                xn.z = fmaf(fc, G[j].z, xn.z); xn.w = fmaf(fc, G[j].w, xn.w);
            }
        float fk = nphi[k];
        xn.x = fmaf(fk, gk.x, xn.x); xn.y = fmaf(fk, gk.y, xn.y);
        xn.z = fmaf(fk, gk.z, xn.z); xn.w = fmaf(fk, gk.w, xn.w);

        float a[4] = {xn.x, xn.y, xn.z, xn.w};
        ushort_t hh[4], ll[4];
#pragma unroll
        for (int j = 0; j < 4; ++j) { hh[j] = f2bf(a[j]); ll[j] = f2bf(a[j] - bf2f(hh[j])); }
        ushort4 h = {hh[0],hh[1],hh[2],hh[3]}, l = {ll[0],ll[1],ll[2],ll[3]};
        size_t ab = (size_t)b * KA + col;
        *(ushort4*)(Azz + ab) = h; *(ushort4*)(Azz + ab + DD) = l;
    }
}

// ---------------- final: argmin obj; out = x_bk + g_bk from bf16 planes ----------------
__global__ __launch_bounds__(256)
void final_out(const ushort_t* __restrict__ gxp, const float* __restrict__ state,
               const float* __restrict__ scal, float* __restrict__ out) {
    const int i4 = blockIdx.x * 256 + threadIdx.x;
    float best = scal[0];
    int bk = 0;
#pragma unroll
    for (int k = 1; k <= TT; ++k) {
        float o = scal[k];
        if (o < best) { best = o; bk = k; }
    }
    const size_t idx = (size_t)i4 * 4;
    const int m = (int)(idx >> 11);
    const float* cf = state + (size_t)m * ST_SZ + ST_XSN + bk * 13;
    ushort4 gb = *(const ushort4*)(gxp + (size_t)bk * BD + idx);
    float4 r = { bf2f(gb.x), bf2f(gb.y), bf2f(gb.z), bf2f(gb.w) };
    for (int j = 0; j < bk; ++j) {
        float c1 = cf[j];
        ushort4 gu = *(const ushort4*)(gxp + (size_t)j * BD + idx);
        r.x = fmaf(c1, bf2f(gu.x), r.x); r.y = fmaf(c1, bf2f(gu.y), r.y);
        r.z = fmaf(c1, bf2f(gu.z), r.z); r.w = fmaf(c1, bf2f(gu.w), r.w);
    }
    ((float4*)out)[i4] = r;
}

// ---------------- launch ----------------
extern "C" void kernel_launch(void* const* d_in, const int* in_sizes, int n_in,
                              void* d_out, int out_size, void* d_ws, size_t ws_size,
                              hipStream_t stream) {
    const float* xin  = (const float*)d_in[0];
    const float* W    = (const float*)d_in[2];
    const float* U    = (const float*)d_in[3];
    const float* bias = (const float*)d_in[4];
    float* out = (float*)d_out;

    float* ws = (float*)d_ws;
    float* c      = ws;                                   // 1 BD
    float* y      = ws + 1 * (size_t)BD;                  // 8 BD
    ushort_t* gxp = (ushort_t*)(ws + 9 * (size_t)BD);     // 13 bf16 planes = 6.5 BD
    ushort_t* Axx = (ushort_t*)(ws + 16 * (size_t)BD);    // 1 BD
    ushort_t* Azz = (ushort_t*)(ws + 17 * (size_t)BD);    // 1 BD
    ushort_t* Wt  = (ushort_t*)(ws + 18 * (size_t)BD);    // [2048][2048]u16 = 4 BD
    ushort_t* Ut  = (ushort_t*)(ws + 22 * (size_t)BD);    // 4 BD
    float* state  = ws + 26 * (size_t)BD;                 // 0.5 BD
    float* scal   = state + (size_t)BB * ST_SZ;           // 32 floats

    convert_w<<<dim3(32, 32, 2), 256, 0, stream>>>(W, U, Wt, Ut);
    init_misc<<<512, 256, 0, stream>>>(xin, Axx, state);

    dim3 gg(32, NKS);   // 256 blocks
    gemm_bf16s<<<gg, 512, 0, stream>>>(Axx, Ut, y);
    epi0<<<BB, 512, 0, stream>>>(y, bias, c, gxp, Azz, state, scal);

    for (int k = 1; k <= TT; ++k) {
        gemm_bf16s<<<gg, 512, 0, stream>>>(Azz, Wt, y);
        broyden_gram<<<BB, 512, 0, stream>>>(y, c, gxp, Azz, state, scal, k);
    }

    final_out<<<512, 256, 0, stream>>>(gxp, state, scal, out);
}

// Round 12
// 367.624 us; speedup vs baseline: 4.9729x; 1.1636x over previous
//
#include <hip/hip_runtime.h>
#include <math.h>

// DEQ fixed-point via Broyden. B=256, D=2048, T=12.
// R12: loop GEMMs single-plane bf16 A (K=2048; x is tanh-scaled so bf16-x error
// ~ W-bf16 error, absmax forecast 3-4 bf16 ulp) + fp16 y partials (error ~1e-4,
// negligible). k=0 GEMM keeps hi|lo A (K=4096) + fp32 y, since xin~N(0,1) error
// enters c and all iterations. Separate kernels per phase (in-kernel grid
// barriers 5-10x slower on MI355X — R5+R9). Gram-space Broyden, bf16 g-planes.

#define DD 2048
#define KA 4096            // Axx (k0) stride: [hi|lo]
#define KW 2048
#define BB 256
#define BD (BB * DD)
#define TT 12
#define NKS 8

// state layout (floats, per row, stride 1024)
#define ST_S   0           // 169
#define ST_A   169         // 12*13
#define ST_B   325         // 12*13
#define ST_PHI 481         // 13
#define ST_XI  494         // 13
#define ST_XSN 507         // 13*13
#define ST_SZ  1024

typedef unsigned short ushort_t;
typedef _Float16 half_t;
typedef __attribute__((ext_vector_type(8))) short short8;
typedef __attribute__((ext_vector_type(4))) float floatx4;
typedef __attribute__((ext_vector_type(4))) _Float16 half4;

__device__ __forceinline__ ushort_t f2bf(float f) {
    unsigned int u = __float_as_uint(f);
    unsigned int r = (u + 0x7FFFu + ((u >> 16) & 1u)) >> 16;
    return (ushort_t)r;
}
__device__ __forceinline__ float bf2f(ushort_t h) {
    return __uint_as_float(((unsigned int)h) << 16);
}
__device__ __forceinline__ void gload_lds16(const void* g, void* l) {
    __builtin_amdgcn_global_load_lds(
        (const __attribute__((address_space(1))) unsigned int*)g,
        (__attribute__((address_space(3))) unsigned int*)l, 16, 0, 0);
}
__device__ __forceinline__ float wave_red(float v) {
#pragma unroll
    for (int off = 32; off > 0; off >>= 1) v += __shfl_down(v, off, 64);
    return v;
}

// ---------------- W & U -> bf16 transposed [n][k] planes ----------------
__global__ __launch_bounds__(256)
void convert_w(const float* __restrict__ W, const float* __restrict__ U,
               ushort_t* __restrict__ Wt, ushort_t* __restrict__ Ut) {
    const float* src = blockIdx.z ? U : W;
    ushort_t* dst = blockIdx.z ? Ut : Wt;
    __shared__ ushort_t Hs[64][65];
    const int tid = threadIdx.x;
    const int k0 = blockIdx.y * 64, n0 = blockIdx.x * 64;
    const int r = tid >> 4, c4 = (tid & 15) * 4;
#pragma unroll
    for (int i = 0; i < 4; ++i) {
        int kr = r + i * 16;
        float4 w = *(const float4*)(src + (size_t)(k0 + kr) * DD + n0 + c4);
        Hs[kr][c4 + 0] = f2bf(w.x); Hs[kr][c4 + 1] = f2bf(w.y);
        Hs[kr][c4 + 2] = f2bf(w.z); Hs[kr][c4 + 3] = f2bf(w.w);
    }
    __syncthreads();
#pragma unroll
    for (int i = 0; i < 4; ++i) {
        int nr = r + i * 16;
        ushort4 hv = { Hs[c4+0][nr], Hs[c4+1][nr], Hs[c4+2][nr], Hs[c4+3][nr] };
        *(ushort4*)(dst + (size_t)(n0 + nr) * KW + (size_t)(k0 + c4)) = hv;
    }
}

// ---------------- init: Axx = [hi|lo](xin); zero state+scal ----------------
__global__ void init_misc(const float* __restrict__ xin, ushort_t* __restrict__ Axx,
                          float* __restrict__ stbase) {
    const int i4 = blockIdx.x * 256 + threadIdx.x;   // 512 blocks
    const int idx = i4 * 4;
    const int m = idx >> 11, col = idx & 2047;
    float4 xv = ((const float4*)xin)[i4];
    float a[4] = {xv.x, xv.y, xv.z, xv.w};
    ushort_t hh[4], ll[4];
#pragma unroll
    for (int j = 0; j < 4; ++j) { hh[j] = f2bf(a[j]); ll[j] = f2bf(a[j] - bf2f(hh[j])); }
    ushort4 h = {hh[0],hh[1],hh[2],hh[3]}, l = {ll[0],ll[1],ll[2],ll[3]};
    size_t ab = (size_t)m * KA + col;
    *(ushort4*)(Axx + ab) = h; *(ushort4*)(Axx + ab + DD) = l;
    if (i4 < 65544) {            // state 262144 + scal 32 floats
        float4 z = {0.f, 0.f, 0.f, 0.f};
        ((float4*)stbase)[i4] = z;
    }
}

// ---------------- M-resident GEMM (templated on K geometry and y dtype) ----------------
// grid (32, NKS): x = n-tile (64), y = ks. A row stride LDA; A k-off = ks*KSLICE;
// W k-off = (ks&BMOD)*KSLICE. 512 thr = 8 waves, wave-tile 64x32.
// A chunk 256x64 (32 KB) + B 64x64 (8 KB), double-buffered.
template<int LDA, int KSLICE, int NIT, int BMOD, typename YT>
__global__ __launch_bounds__(512)
void gemm_t(const ushort_t* __restrict__ A, const ushort_t* __restrict__ Bt,
            YT* __restrict__ y) {
    __shared__ ushort_t As[2][256 * 64];   // 2 x 32 KB
    __shared__ ushort_t Bs[2][64 * 64];    // 2 x 8 KB
    const int tid = threadIdx.x;
    const int lane = tid & 63, w = tid >> 6;
    const int bn = blockIdx.x * 64;
    const int ks = blockIdx.y;
    const int waveM = w >> 1, waveN = w & 1;

    const int srow = tid >> 3;
    const int sg = (tid & 7) ^ (srow & 7);
    const ushort_t* Ag = A  + (size_t)srow * LDA + ks * KSLICE + sg * 8;
    const ushort_t* Bg = Bt + (size_t)(bn + srow) * KW + (ks & BMOD) * KSLICE + sg * 8;
    const size_t rs64 = (size_t)64 * LDA;

    const int q = lane >> 4, rl = lane & 15;
    int offA[2][4], offB[2][2];
#pragma unroll
    for (int kk = 0; kk < 2; ++kk) {
        int j = kk * 4 + q;
#pragma unroll
        for (int mi = 0; mi < 4; ++mi) {
            int m = waveM * 64 + mi * 16 + rl;
            offA[kk][mi] = (m * 8 + (j ^ (m & 7))) * 8;
        }
#pragma unroll
        for (int ni = 0; ni < 2; ++ni) {
            int n = waveN * 32 + ni * 16 + rl;
            offB[kk][ni] = (n * 8 + (j ^ (n & 7))) * 8;
        }
    }

    floatx4 acc[4][2];
#pragma unroll
    for (int mi = 0; mi < 4; ++mi)
#pragma unroll
        for (int ni = 0; ni < 2; ++ni) acc[mi][ni] = (floatx4){0.f,0.f,0.f,0.f};

    gload_lds16(Ag,            As[0] + tid * 8);
    gload_lds16(Ag + rs64,     As[0] + (512 + tid) * 8);
    gload_lds16(Ag + 2 * rs64, As[0] + (1024 + tid) * 8);
    gload_lds16(Ag + 3 * rs64, As[0] + (1536 + tid) * 8);
    gload_lds16(Bg,            Bs[0] + tid * 8);
    Ag += 64; Bg += 64;
    __syncthreads();

    for (int it = 0; it < NIT; ++it) {
        const int cur = it & 1, nxt = cur ^ 1;
        if (it + 1 < NIT) {
            gload_lds16(Ag,            As[nxt] + tid * 8);
            gload_lds16(Ag + rs64,     As[nxt] + (512 + tid) * 8);
            gload_lds16(Ag + 2 * rs64, As[nxt] + (1024 + tid) * 8);
            gload_lds16(Ag + 3 * rs64, As[nxt] + (1536 + tid) * 8);
            gload_lds16(Bg,            Bs[nxt] + tid * 8);
            Ag += 64; Bg += 64;
        }
        const ushort_t* Ab = As[cur];
        const ushort_t* Bb = Bs[cur];
#pragma unroll
        for (int kk = 0; kk < 2; ++kk) {
            short8 b0 = *(const short8*)(Bb + offB[kk][0]);
            short8 b1 = *(const short8*)(Bb + offB[kk][1]);
#pragma unroll
            for (int mi = 0; mi < 4; ++mi) {
                short8 a = *(const short8*)(Ab + offA[kk][mi]);
                acc[mi][0] = __builtin_amdgcn_mfma_f32_16x16x32_bf16(a, b0, acc[mi][0], 0, 0, 0);
                acc[mi][1] = __builtin_amdgcn_mfma_f32_16x16x32_bf16(a, b1, acc[mi][1], 0, 0, 0);
            }
        }
        __syncthreads();
    }

    YT* yp = y + (size_t)ks * BD;
    const int mb = waveM * 64 + q * 4;
    const int nb = bn + waveN * 32 + rl;
#pragma unroll
    for (int mi = 0; mi < 4; ++mi)
#pragma unroll
        for (int r = 0; r < 4; ++r) {
            yp[(size_t)(mb + mi * 16 + r) * DD + nb]      = (YT)acc[mi][0][r];
            yp[(size_t)(mb + mi * 16 + r) * DD + nb + 16] = (YT)acc[mi][1][r];
        }
}

// ---------------- step 0: c, g0 = tanh(c) (bf16 plane), Azz, state init ----------------
// reads fp32 y (k=0 gemm writes fp32 for accuracy of c)
__global__ __launch_bounds__(512)
void epi0(const float* __restrict__ y, const float* __restrict__ bias,
          float* __restrict__ c, ushort_t* __restrict__ gxp,
          ushort_t* __restrict__ Azz, float* __restrict__ state,
          float* __restrict__ scal) {
    __shared__ float red[8];
    const int tid = threadIdx.x;
    const int b = blockIdx.x;
    const int col = tid * 4;
    const size_t base = (size_t)b * DD + col;

    float4 cc = *(const float4*)(bias + col);
#pragma unroll
    for (int s = 0; s < NKS; ++s) {
        float4 v = *(const float4*)(y + (size_t)s * BD + base);
        cc.x += v.x; cc.y += v.y; cc.z += v.z; cc.w += v.w;
    }
    *(float4*)(c + base) = cc;
    float4 g = { tanhf(cc.x), tanhf(cc.y), tanhf(cc.z), tanhf(cc.w) };
    ushort4 gs = { f2bf(g.x), f2bf(g.y), f2bf(g.z), f2bf(g.w) };
    *(ushort4*)(gxp + base) = gs;
    *(ushort4*)(Azz + base) = gs;     // x1 = g0, single bf16 plane

    float pd = g.x*g.x + g.y*g.y + g.z*g.z + g.w*g.w;
    pd = wave_red(pd);
    if ((tid & 63) == 0) red[tid >> 6] = pd;
    __syncthreads();
    if (tid == 0) {
        float t = 0.f;
#pragma unroll
        for (int w2 = 0; w2 < 8; ++w2) t += red[w2];
        float* stb = state + (size_t)b * ST_SZ;
        stb[ST_S + 0]   = t;
        stb[ST_PHI + 0] = 1.f;
        stb[ST_XI + 0]  = 1.f;
        atomicAdd(&scal[0], t);
    }
}

// ---------------- Gram-space Broyden (bf16 g-planes, fp16 y) ----------------
__global__ __launch_bounds__(512)
void broyden_gram(const half_t* __restrict__ yh, const float* __restrict__ c,
                  ushort_t* __restrict__ gxp, ushort_t* __restrict__ Azz,
                  float* __restrict__ state, float* __restrict__ scal, int k)
{
    __shared__ float red[8][16];
    __shared__ float dots[14];
    __shared__ float Sl[169], Al[156], Bl[156], PHl[13], XIl[13];
    __shared__ float newA[14], newB[14], nphi[14];
    __shared__ double dyv[13], dxtu[12], dvdg[12], dcgx[13], dden[1];
    const int tid = threadIdx.x;
    const int lane = tid & 63, w = tid >> 6;
    const int b = blockIdx.x;
    const int p = k - 1;
    float* stb = state + (size_t)b * ST_SZ;

    for (int i = tid; i < 169; i += 512) Sl[i] = stb[ST_S + i];
    for (int i = tid; i < 156; i += 512) { Al[i] = stb[ST_A + i]; Bl[i] = stb[ST_B + i]; }
    if (tid < 13) { PHl[tid] = stb[ST_PHI + tid]; XIl[tid] = stb[ST_XI + tid]; }

    const int col = tid * 4;
    const size_t base = (size_t)b * DD + col;
    float4 pre = *(const float4*)(c + base);
#pragma unroll
    for (int s = 0; s < NKS; ++s) {
        half4 v = *(const half4*)(yh + (size_t)s * BD + base);
        pre.x += (float)v.x; pre.y += (float)v.y;
        pre.z += (float)v.z; pre.w += (float)v.w;
    }

    float4 G[12];
#pragma unroll
    for (int j = 0; j < 12; ++j)
        if (j < k) {
            ushort4 gu = *(const ushort4*)(gxp + (size_t)j * BD + base);
            G[j] = (float4){ bf2f(gu.x), bf2f(gu.y), bf2f(gu.z), bf2f(gu.w) };
        }

    __syncthreads();

    float4 x = {0.f, 0.f, 0.f, 0.f};
#pragma unroll
    for (int j = 0; j < 12; ++j)
        if (j < k) {
            float xc = XIl[j];
            x.x = fmaf(xc, G[j].x, x.x); x.y = fmaf(xc, G[j].y, x.y);
            x.z = fmaf(xc, G[j].z, x.z); x.w = fmaf(xc, G[j].w, x.w);
        }
    float4 gk = { tanhf(pre.x) - x.x, tanhf(pre.y) - x.y,
                  tanhf(pre.z) - x.z, tanhf(pre.w) - x.w };

#pragma unroll
    for (int j = 0; j < 12; ++j)
        if (j < k) {
            float pd = G[j].x*gk.x + G[j].y*gk.y + G[j].z*gk.z + G[j].w*gk.w;
            pd = wave_red(pd);
            if (lane == 0) red[w][j] = pd;
        }
    {
        float pdk = gk.x*gk.x + gk.y*gk.y + gk.z*gk.z + gk.w*gk.w;
        pdk = wave_red(pdk);
        if (lane == 0) red[w][k] = pdk;
    }
    __syncthreads();
    if (tid <= k) {
        float s = 0.f;
#pragma unroll
        for (int w2 = 0; w2 < 8; ++w2) s += red[w2][tid];
        dots[tid] = s;
        if (tid == k) atomicAdd(&scal[k], s);
    }
    __syncthreads();

    // ---- scalar solve (fp64) ----
    if (tid < k) {
        double s = 0.0;
        for (int j = 0; j < k; ++j) s += (double)Sl[tid*13 + j] * (double)PHl[j];
        dyv[tid] = s;
    }
    __syncthreads();
    if (tid < p) {
        double sx = 0.0, sv = 0.0;
        for (int j = 0; j < k; ++j) {
            sx += (double)Al[tid*13 + j] * dyv[j];
            sv += (double)Bl[tid*13 + j] * ((double)dots[j] - (double)Sl[j*13 + (k-1)]);
        }
        dxtu[tid] = sx; dvdg[tid] = sv;
    }
    __syncthreads();
    if (tid < k) {
        double s = -(double)PHl[tid];
        for (int t = 0; t < p; ++t) s += dxtu[t] * (double)Bl[t*13 + tid];
        newB[tid] = (float)s;
    }
    __syncthreads();
    if (tid == 0) {
        double s = 0.0;
        for (int j = 0; j < k; ++j)
            s += (double)newB[j] * ((double)dots[j] - (double)Sl[j*13 + (k-1)]);
        dden[0] = s;
    }
    __syncthreads();
    if (tid <= k) {
        double s = (double)((tid < 13) ? PHl[tid] : 0.f);
        if (tid == k)     s += 1.0;
        if (tid == k - 1) s -= 1.0;
        for (int t = 0; t < p; ++t) s -= dvdg[t] * (double)Al[t*13 + tid];
        newA[tid] = (float)(s / dden[0]);
    }
    if (tid >= 32 && tid < 32 + p) {
        int t = tid - 32;
        double s = 0.0;
        for (int j = 0; j < k; ++j) s += (double)Bl[t*13 + j] * (double)dots[j];
        dcgx[t] = s;
    }
    if (tid == 63) {
        double s = 0.0;
        for (int j = 0; j < k; ++j) s += (double)newB[j] * (double)dots[j];
        dcgx[p] = s;
    }
    __syncthreads();
    if (tid <= k) {
        double s = (tid == k) ? 1.0 : 0.0;
        for (int t = 0; t < p; ++t) s -= dcgx[t] * (double)Al[t*13 + tid];
        s -= dcgx[p] * (double)newA[tid];
        nphi[tid] = (float)s;
    }
    __syncthreads();

    if (tid <= k) {
        stb[ST_S + k*13 + tid] = dots[tid];
        stb[ST_S + tid*13 + k] = dots[tid];
        stb[ST_A + p*13 + tid] = newA[tid];
        stb[ST_PHI + tid] = nphi[tid];
        float xi_old = (tid < 13) ? XIl[tid] : 0.f;
        stb[ST_XI + tid] = xi_old + nphi[tid];
    }
    if (tid < k) stb[ST_B + p*13 + tid] = newB[tid];
    if (tid < 13) stb[ST_XSN + k*13 + tid] = XIl[tid];   // coeffs of x_k

    // g_k plane always needed (final may pick bk=k)
    {
        ushort4 gs = { f2bf(gk.x), f2bf(gk.y), f2bf(gk.z), f2bf(gk.w) };
        *(ushort4*)(gxp + (size_t)k * BD + base) = gs;
    }

    if (k < TT) {   // x_{k+1}/Azz dead at k=TT
        float4 xn = x;
#pragma unroll
        for (int j = 0; j < 12; ++j)
            if (j < k) {
                float fc = nphi[j];
                xn.x = fmaf(fc, G[j].x, xn.x); xn.y = fmaf(fc, G[j].y, xn.y);
                xn.z = fmaf(fc, G[j].z, xn.z); xn.w = fmaf(fc, G[j].w, xn.w);
            }
        float fk = nphi[k];
        xn.x = fmaf(fk, gk.x, xn.x); xn.y = fmaf(fk, gk.y, xn.y);
        xn.z = fmaf(fk, gk.z, xn.z); xn.w = fmaf(fk, gk.w, xn.w);

        ushort4 h = { f2bf(xn.x), f2bf(xn.y), f2bf(xn.z), f2bf(xn.w) };
        *(ushort4*)(Azz + base) = h;              // single bf16 plane
    }
}

// ---------------- final: argmin obj; out = x_bk + g_bk from bf16 planes ----------------
__global__ __launch_bounds__(256)
void final_out(const ushort_t* __restrict__ gxp, const float* __restrict__ state,
               const float* __restrict__ scal, float* __restrict__ out) {
    const int i4 = blockIdx.x * 256 + threadIdx.x;
    float best = scal[0];
    int bk = 0;
#pragma unroll
    for (int k = 1; k <= TT; ++k) {
        float o = scal[k];
        if (o < best) { best = o; bk = k; }
    }
    const size_t idx = (size_t)i4 * 4;
    const int m = (int)(idx >> 11);
    const float* cf = state + (size_t)m * ST_SZ + ST_XSN + bk * 13;
    ushort4 gb = *(const ushort4*)(gxp + (size_t)bk * BD + idx);
    float4 r = { bf2f(gb.x), bf2f(gb.y), bf2f(gb.z), bf2f(gb.w) };
    for (int j = 0; j < bk; ++j) {
        float c1 = cf[j];
        ushort4 gu = *(const ushort4*)(gxp + (size_t)j * BD + idx);
        r.x = fmaf(c1, bf2f(gu.x), r.x); r.y = fmaf(c1, bf2f(gu.y), r.y);
        r.z = fmaf(c1, bf2f(gu.z), r.z); r.w = fmaf(c1, bf2f(gu.w), r.w);
    }
    ((float4*)out)[i4] = r;
}

// ---------------- launch ----------------
extern "C" void kernel_launch(void* const* d_in, const int* in_sizes, int n_in,
                              void* d_out, int out_size, void* d_ws, size_t ws_size,
                              hipStream_t stream) {
    const float* xin  = (const float*)d_in[0];
    const float* W    = (const float*)d_in[2];
    const float* U    = (const float*)d_in[3];
    const float* bias = (const float*)d_in[4];
    float* out = (float*)d_out;

    float* ws = (float*)d_ws;
    float* c      = ws;                                   // 1 BD
    float* y      = ws + 1 * (size_t)BD;                  // 8 BD fp32 (k0) / fp16 (loop)
    ushort_t* gxp = (ushort_t*)(ws + 9 * (size_t)BD);     // 13 bf16 planes = 6.5 BD
    ushort_t* Axx = (ushort_t*)(ws + 16 * (size_t)BD);    // [256][4096] u16 = 1 BD
    ushort_t* Azz = (ushort_t*)(ws + 17 * (size_t)BD);    // [256][2048] u16 = 0.5 BD
    ushort_t* Wt  = (ushort_t*)(ws + 18 * (size_t)BD);    // 4 BD
    ushort_t* Ut  = (ushort_t*)(ws + 22 * (size_t)BD);    // 4 BD
    float* state  = ws + 26 * (size_t)BD;                 // 0.5 BD
    float* scal   = state + (size_t)BB * ST_SZ;           // 32 floats

    convert_w<<<dim3(32, 32, 2), 256, 0, stream>>>(W, U, Wt, Ut);
    init_misc<<<512, 256, 0, stream>>>(xin, Axx, state);

    dim3 gg(32, NKS);   // 256 blocks
    // k=0: hi|lo A (K=4096), fp32 y
    gemm_t<4096, 512, 8, 3, float><<<gg, 512, 0, stream>>>(Axx, Ut, y);
    epi0<<<BB, 512, 0, stream>>>(y, bias, c, gxp, Azz, state, scal);

    for (int k = 1; k <= TT; ++k) {
        // loop: single bf16 A (K=2048), fp16 y
        gemm_t<2048, 256, 4, 7, half_t><<<gg, 512, 0, stream>>>(Azz, Wt, (half_t*)y);
        broyden_gram<<<BB, 512, 0, stream>>>((const half_t*)y, c, gxp, Azz, state, scal, k);
    }

    final_out<<<512, 256, 0, stream>>>(gxp, state, scal, out);
}